// Round 11
// baseline (480.241 us; speedup 1.0000x reference)
//
#include <hip/hip_runtime.h>
#include <hip/hip_bf16.h>
#include <cstdint>
#include <cstddef>

// Problem constants
#define NN 20000
#define EE 320000
#define ET (EE + NN)     // edges + self loops
#define MPAD 20096       // 157 * 128, M padded to tile
#define BNP 256          // BN stage-1 partial blocks (deterministic)
#define SCHUNK 20        // scan_fast: counts per thread (1024*20 >= NN)

typedef __attribute__((ext_vector_type(8))) short  short8;   // 8 bf16 (4 VGPRs)
typedef __attribute__((ext_vector_type(4))) float  floatx4;  // MFMA C/D frag

__device__ inline unsigned short f2bf(float f) {   // RNE fp32 -> bf16
    unsigned u = __float_as_uint(f);
    u += 0x7FFFu + ((u >> 16) & 1u);
    return (unsigned short)(u >> 16);
}
__device__ inline float bf2f(unsigned short b) {
    return __uint_as_float(((unsigned)b) << 16);
}
// packed bf16x2 in a uint -> two floats
__device__ inline float bflo(unsigned u) { return __uint_as_float(u << 16); }
__device__ inline float bfhi(unsigned u) { return __uint_as_float(u & 0xFFFF0000u); }

// per-H gather vector type: lane covers H channels = 2H bytes
template <int H> struct VecT;
template <> struct VecT<8> { using T = uint4; };
template <> struct VecT<4> { using T = uint2; };
template <> struct VecT<2> { using T = unsigned; };

// ---------------------------------------------------------------------------
// Utility kernels
// ---------------------------------------------------------------------------
__global__ void zero_i32(int* __restrict__ p, int n) {
    int i = blockIdx.x * blockDim.x + threadIdx.x;
    if (i < n) p[i] = 0;
}

// fp32 [M,K] -> bf16 [Mpad,K], rows >= M zero-filled. 4 elems/thread.
__global__ void cvt_a_bf16(const float* __restrict__ in, unsigned short* __restrict__ out,
                           int M, int Mpad, int K) {
    long long base = ((long long)blockIdx.x * blockDim.x + threadIdx.x) * 4;
    if (base >= (long long)Mpad * K) return;
    int row = (int)(base / K);
    float4 v = make_float4(0.f, 0.f, 0.f, 0.f);
    if (row < M) v = *(const float4*)(in + base);
    ushort4 o;
    o.x = f2bf(v.x); o.y = f2bf(v.y); o.z = f2bf(v.z); o.w = f2bf(v.w);
    *(ushort4*)(out + base) = o;
}

// W [K,N] fp32 -> Wt [N,K] bf16 (once per launch; small)
__global__ void cvt_w_t(const float* __restrict__ W, unsigned short* __restrict__ Wt,
                        int K, int N) {
    int i = blockIdx.x * blockDim.x + threadIdx.x;
    if (i >= K * N) return;
    int k = i / N, n = i - k * N;
    Wt[(size_t)n * K + k] = f2bf(W[i]);
}

// ---------------------------------------------------------------------------
// CSR build: count -> scan_fast -> fill
// scan_fast: 1 block x 1024 thr; thread t serially scans its 20 contiguous
// counts in registers; one 1024-wide LDS Hillis-Steele (20 barriers, not 400).
// ---------------------------------------------------------------------------
__global__ void count_edges(const int* __restrict__ dst, int* __restrict__ cnt) {
    int e = blockIdx.x * blockDim.x + threadIdx.x;
    if (e >= ET) return;
    int d = (e < EE) ? dst[e] : (e - EE);
    atomicAdd(&cnt[d], 1);
}

__global__ __launch_bounds__(1024) void scan_fast(const int* __restrict__ cnt,
                                                  int* __restrict__ rowp,
                                                  int* __restrict__ wptr, int n) {
    __shared__ int sums[1024];
    const int t = threadIdx.x;
    const int base = t * SCHUNK;
    int local[SCHUNK];
    int acc = 0;
#pragma unroll
    for (int i = 0; i < SCHUNK; ++i) {
        int idx = base + i;
        int v = (idx < n) ? cnt[idx] : 0;
        local[i] = acc;          // exclusive within thread
        acc += v;
    }
    sums[t] = acc;
    __syncthreads();
    for (int o = 1; o < 1024; o <<= 1) {
        int u = (t >= o) ? sums[t - o] : 0;
        __syncthreads();
        sums[t] += u;
        __syncthreads();
    }
    int excl = sums[t] - acc;    // exclusive prefix of this thread's range
#pragma unroll
    for (int i = 0; i < SCHUNK; ++i) {
        int idx = base + i;
        if (idx < n) { int rp = excl + local[i]; rowp[idx] = rp; wptr[idx] = rp; }
    }
    if (t == 1023) rowp[n] = sums[1023];
}

__global__ void fill_edges(const int* __restrict__ src, const int* __restrict__ dst,
                           int* __restrict__ wptr, int* __restrict__ colx) {
    int e = blockIdx.x * blockDim.x + threadIdx.x;
    if (e >= ET) return;
    int s, d;
    if (e < EE) { s = src[e]; d = dst[e]; } else { s = e - EE; d = e - EE; }
    int pos = atomicAdd(&wptr[d], 1);
    colx[pos] = s;
}

// ---------------------------------------------------------------------------
// BF16 MFMA GEMM with fused epilogue (node-major outputs):
//   - hN[row][col] bf16  (node-major h, col = head*64 + c)
//   - aS[row][head], aD[row][head] fp32 (attention dots), H = N/64
// C[M,N] = A[Mpad,K] * Bt[N,K]^T. 128x128 tile, 4 waves, 16x16x32 MFMA.
// ---------------------------------------------------------------------------
__global__ __launch_bounds__(256) void gemm_bf16_fused(
        const unsigned short* __restrict__ A, const unsigned short* __restrict__ Bt,
        unsigned short* __restrict__ hN, float* __restrict__ aS, float* __restrict__ aD,
        const float* __restrict__ atts, const float* __restrict__ attd,
        int M, int N, int K) {
    __shared__ unsigned short As[128][40];
    __shared__ unsigned short Bs[128][40];
    const int t = threadIdx.x;
    const int lane = t & 63, wave = t >> 6;
    const int wm = wave >> 1, wn = wave & 1;
    const int quad = lane >> 4, mrow = lane & 15;
    const int row0 = blockIdx.y * 128, col0 = blockIdx.x * 128;
    const int srow = t >> 2, schunk = (t & 3) * 8;
    const int H = N >> 6;

    floatx4 acc[4][4];
#pragma unroll
    for (int i = 0; i < 4; ++i)
#pragma unroll
        for (int j = 0; j < 4; ++j)
#pragma unroll
            for (int r = 0; r < 4; ++r) acc[i][j][r] = 0.f;

    for (int k0 = 0; k0 < K; k0 += 32) {
        uint4 ra0 = *(const uint4*)(A  + (size_t)(row0 + srow)      * K + k0 + schunk);
        uint4 ra1 = *(const uint4*)(A  + (size_t)(row0 + srow + 64) * K + k0 + schunk);
        uint4 rb0 = *(const uint4*)(Bt + (size_t)(col0 + srow)      * K + k0 + schunk);
        uint4 rb1 = *(const uint4*)(Bt + (size_t)(col0 + srow + 64) * K + k0 + schunk);
        __syncthreads();
        *(uint4*)&As[srow][schunk]      = ra0;
        *(uint4*)&As[srow + 64][schunk] = ra1;
        *(uint4*)&Bs[srow][schunk]      = rb0;
        *(uint4*)&Bs[srow + 64][schunk] = rb1;
        __syncthreads();

        short8 af[4], bfr[4];
#pragma unroll
        for (int i = 0; i < 4; ++i)
            af[i] = *(const short8*)&As[wm * 64 + i * 16 + mrow][quad * 8];
#pragma unroll
        for (int j = 0; j < 4; ++j)
            bfr[j] = *(const short8*)&Bs[wn * 64 + j * 16 + mrow][quad * 8];
#pragma unroll
        for (int i = 0; i < 4; ++i)
#pragma unroll
            for (int j = 0; j < 4; ++j)
                acc[i][j] = __builtin_amdgcn_mfma_f32_16x16x32_bf16(af[i], bfr[j], acc[i][j], 0, 0, 0);
    }

    // ---- fused epilogue ----
    const int head = (col0 + wn * 64) >> 6;
    float attS[4], attD[4];
#pragma unroll
    for (int j = 0; j < 4; ++j) {
        attS[j] = atts[head * 64 + j * 16 + mrow];
        attD[j] = attd[head * 64 + j * 16 + mrow];
    }

#pragma unroll
    for (int i = 0; i < 4; ++i) {
#pragma unroll
        for (int r = 0; r < 4; ++r) {
            int row = row0 + wm * 64 + i * 16 + quad * 4 + r;
            float ps = acc[i][0][r] * attS[0] + acc[i][1][r] * attS[1]
                     + acc[i][2][r] * attS[2] + acc[i][3][r] * attS[3];
            float pd = acc[i][0][r] * attD[0] + acc[i][1][r] * attD[1]
                     + acc[i][2][r] * attD[2] + acc[i][3][r] * attD[3];
#pragma unroll
            for (int o = 1; o < 16; o <<= 1) {
                ps += __shfl_xor(ps, o);
                pd += __shfl_xor(pd, o);
            }
            if (row < M) {
                if (mrow == 0) {
                    aS[(size_t)row * H + head] = ps;
                    aD[(size_t)row * H + head] = pd;
                }
#pragma unroll
                for (int j = 0; j < 4; ++j)
                    hN[(size_t)row * N + col0 + wn * 64 + j * 16 + mrow] = f2bf(acc[i][j][r]);
            }
        }
    }
}

// ---------------------------------------------------------------------------
// GAT aggregation, all heads per wave. Fast path for degree <= 64 (dominant:
// mean degree ~17): e[h] computed ONCE, probs written directly -> saves the
// second colx load, H aS reloads, H leaky and H exp per edge vs two-pass.
// Fallback: two-pass flash for degree > 64.
// ---------------------------------------------------------------------------
template <int H>
__global__ __launch_bounds__(256) void gat_agg_all(
        const unsigned short* __restrict__ hN,
        const float* __restrict__ aS, const float* __restrict__ aD,
        const int* __restrict__ rowp, const int* __restrict__ colx,
        const float* __restrict__ bias, float* __restrict__ out, int Nn) {
    constexpr int F = H * 64;
    using V = typename VecT<H>::T;
    __shared__ float pbuf[4][64 * H];
    __shared__ int   snbuf[4][64];
    const int wave = threadIdx.x >> 6, lane = threadIdx.x & 63;
    const int n = blockIdx.x * 4 + wave;
    if (n >= Nn) return;
    const int hd = (lane * H) >> 6;       // this lane's head
    const int chbase = lane * H;          // flat channel base

    const int b0 = rowp[n], b1 = rowp[n + 1];
    const int deg = b1 - b0;

    float adv[H];
#pragma unroll
    for (int h = 0; h < H; ++h) adv[h] = aD[(size_t)n * H + h];   // broadcast

    float acc[H];
#pragma unroll
    for (int h = 0; h < H; ++h) acc[h] = 0.f;

    if (deg <= 64) {
        // ---------------- fast path: single chunk ----------------
        const int cnt = deg;
        float e[H];
#pragma unroll
        for (int h = 0; h < H; ++h) e[h] = -1e30f;
        if (lane < cnt) {
            int sn = colx[b0 + lane];
            snbuf[wave][lane] = sn;
#pragma unroll
            for (int h = 0; h < H; ++h) {
                float tt = aS[(size_t)sn * H + h] + adv[h];
                e[h] = (tt > 0.f) ? tt : 0.2f * tt;
            }
        }
#pragma unroll
        for (int h = 0; h < H; ++h) {
            float mc = e[h];
#pragma unroll
            for (int o = 32; o > 0; o >>= 1) mc = fmaxf(mc, __shfl_xor(mc, o));
            float p = (lane < cnt) ? __expf(e[h] - mc) : 0.f;
            float ps = p;
#pragma unroll
            for (int o = 32; o > 0; o >>= 1) ps += __shfl_xor(ps, o);
            if (lane < cnt) pbuf[wave][lane * H + h] = p / ps;
        }
        __threadfence_block();

        int j = 0;
        for (; j + 4 <= cnt; j += 4) {
            int s0 = snbuf[wave][j],     s1 = snbuf[wave][j + 1];
            int s2 = snbuf[wave][j + 2], s3 = snbuf[wave][j + 3];
            float p0 = pbuf[wave][(j + 0) * H + hd];
            float p1 = pbuf[wave][(j + 1) * H + hd];
            float p2 = pbuf[wave][(j + 2) * H + hd];
            float p3 = pbuf[wave][(j + 3) * H + hd];
            V q0 = *(const V*)(hN + (size_t)s0 * F + chbase);
            V q1 = *(const V*)(hN + (size_t)s1 * F + chbase);
            V q2 = *(const V*)(hN + (size_t)s2 * F + chbase);
            V q3 = *(const V*)(hN + (size_t)s3 * F + chbase);
            const unsigned* u0 = (const unsigned*)&q0;
            const unsigned* u1 = (const unsigned*)&q1;
            const unsigned* u2 = (const unsigned*)&q2;
            const unsigned* u3 = (const unsigned*)&q3;
#pragma unroll
            for (int k = 0; k < H / 2; ++k) {
                acc[2 * k]     += p0 * bflo(u0[k]) + p1 * bflo(u1[k]) + p2 * bflo(u2[k]) + p3 * bflo(u3[k]);
                acc[2 * k + 1] += p0 * bfhi(u0[k]) + p1 * bfhi(u1[k]) + p2 * bfhi(u2[k]) + p3 * bfhi(u3[k]);
            }
        }
        for (; j < cnt; ++j) {
            int sj = snbuf[wave][j];
            float pj = pbuf[wave][j * H + hd];
            V q = *(const V*)(hN + (size_t)sj * F + chbase);
            const unsigned* u = (const unsigned*)&q;
#pragma unroll
            for (int k = 0; k < H / 2; ++k) {
                acc[2 * k]     += pj * bflo(u[k]);
                acc[2 * k + 1] += pj * bfhi(u[k]);
            }
        }
    } else {
        // ---------------- fallback: two-pass flash ----------------
        float m[H], s[H];
#pragma unroll
        for (int h = 0; h < H; ++h) { m[h] = -1e30f; s[h] = 0.f; }
        for (int c0 = b0; c0 < b1; c0 += 64) {
            int cnt = min(64, b1 - c0);
            float e[H];
#pragma unroll
            for (int h = 0; h < H; ++h) e[h] = -1e30f;
            if (lane < cnt) {
                int sn = colx[c0 + lane];
#pragma unroll
                for (int h = 0; h < H; ++h) {
                    float tt = aS[(size_t)sn * H + h] + adv[h];
                    e[h] = (tt > 0.f) ? tt : 0.2f * tt;
                }
            }
#pragma unroll
            for (int h = 0; h < H; ++h) {
                float mc = e[h];
#pragma unroll
                for (int o = 32; o > 0; o >>= 1) mc = fmaxf(mc, __shfl_xor(mc, o));
                float nm = fmaxf(m[h], mc);
                s[h] *= __expf(m[h] - nm);
                float p = (lane < cnt) ? __expf(e[h] - nm) : 0.f;
#pragma unroll
                for (int o = 32; o > 0; o >>= 1) p += __shfl_xor(p, o);
                s[h] += p; m[h] = nm;
            }
        }
        float inv[H];
#pragma unroll
        for (int h = 0; h < H; ++h) inv[h] = 1.f / s[h];

        for (int c0 = b0; c0 < b1; c0 += 64) {
            int cnt = min(64, b1 - c0);
            if (lane < cnt) {
                int sn = colx[c0 + lane];
                snbuf[wave][lane] = sn;
#pragma unroll
                for (int h = 0; h < H; ++h) {
                    float tt = aS[(size_t)sn * H + h] + adv[h];
                    tt = (tt > 0.f) ? tt : 0.2f * tt;
                    pbuf[wave][lane * H + h] = __expf(tt - m[h]) * inv[h];
                }
            }
            __threadfence_block();

            int j = 0;
            for (; j + 4 <= cnt; j += 4) {
                int s0 = snbuf[wave][j],     s1 = snbuf[wave][j + 1];
                int s2 = snbuf[wave][j + 2], s3 = snbuf[wave][j + 3];
                float p0 = pbuf[wave][(j + 0) * H + hd];
                float p1 = pbuf[wave][(j + 1) * H + hd];
                float p2 = pbuf[wave][(j + 2) * H + hd];
                float p3 = pbuf[wave][(j + 3) * H + hd];
                V q0 = *(const V*)(hN + (size_t)s0 * F + chbase);
                V q1 = *(const V*)(hN + (size_t)s1 * F + chbase);
                V q2 = *(const V*)(hN + (size_t)s2 * F + chbase);
                V q3 = *(const V*)(hN + (size_t)s3 * F + chbase);
                const unsigned* u0 = (const unsigned*)&q0;
                const unsigned* u1 = (const unsigned*)&q1;
                const unsigned* u2 = (const unsigned*)&q2;
                const unsigned* u3 = (const unsigned*)&q3;
#pragma unroll
                for (int k = 0; k < H / 2; ++k) {
                    acc[2 * k]     += p0 * bflo(u0[k]) + p1 * bflo(u1[k]) + p2 * bflo(u2[k]) + p3 * bflo(u3[k]);
                    acc[2 * k + 1] += p0 * bfhi(u0[k]) + p1 * bfhi(u1[k]) + p2 * bfhi(u2[k]) + p3 * bfhi(u3[k]);
                }
            }
            for (; j < cnt; ++j) {
                int sj = snbuf[wave][j];
                float pj = pbuf[wave][j * H + hd];
                V q = *(const V*)(hN + (size_t)sj * F + chbase);
                const unsigned* u = (const unsigned*)&q;
#pragma unroll
                for (int k = 0; k < H / 2; ++k) {
                    acc[2 * k]     += pj * bflo(u[k]);
                    acc[2 * k + 1] += pj * bfhi(u[k]);
                }
            }
            __threadfence_block();
        }
    }

#pragma unroll
    for (int h = 0; h < H; ++h)
        out[(size_t)n * F + chbase + h] = acc[h] + bias[chbase + h];
}

// ---------------------------------------------------------------------------
// Layer-4 GEMM: A is bf16 [Mpad,K], N=16. Writes bf16 hN and fused attention
// dots aS/aD (H=1, C=16). 64x64 tile; only tx<4 columns are real (N=16).
// ---------------------------------------------------------------------------
__global__ __launch_bounds__(256) void gemm_l4_fused(const unsigned short* __restrict__ A,
                                                     const float* __restrict__ B,
                                                     unsigned short* __restrict__ C,
                                                     float* __restrict__ aS, float* __restrict__ aD,
                                                     const float* __restrict__ atts,
                                                     const float* __restrict__ attd,
                                                     int M, int N, int K) {
    __shared__ float As[16][65];
    __shared__ float Bs[16][64];
    const int tid = threadIdx.x;
    const int tx = tid & 15, ty = tid >> 4;
    const int row0 = blockIdx.y * 64, col0 = blockIdx.x * 64;
    const int rA = tid >> 2, kq = (tid & 3) << 2;
    const int rB = tid >> 4, cq = (tid & 15) << 2;
    float acc[4][4] = {};

    for (int k0 = 0; k0 < K; k0 += 16) {
        ushort4 ha = *(const ushort4*)(A + (size_t)(row0 + rA) * K + k0 + kq);
        float4 fb = make_float4(0.f, 0.f, 0.f, 0.f);
        int bcol = col0 + cq;
        if (bcol < N) fb = *(const float4*)(B + (size_t)(k0 + rB) * N + bcol);
        As[kq + 0][rA] = bf2f(ha.x); As[kq + 1][rA] = bf2f(ha.y);
        As[kq + 2][rA] = bf2f(ha.z); As[kq + 3][rA] = bf2f(ha.w);
        *(float4*)&Bs[rB][cq] = fb;
        __syncthreads();
#pragma unroll
        for (int k = 0; k < 16; ++k) {
            float a0 = As[k][ty * 4 + 0];
            float a1 = As[k][ty * 4 + 1];
            float a2 = As[k][ty * 4 + 2];
            float a3 = As[k][ty * 4 + 3];
            float4 b = *(float4*)&Bs[k][tx * 4];
            acc[0][0] += a0 * b.x; acc[0][1] += a0 * b.y; acc[0][2] += a0 * b.z; acc[0][3] += a0 * b.w;
            acc[1][0] += a1 * b.x; acc[1][1] += a1 * b.y; acc[1][2] += a1 * b.z; acc[1][3] += a1 * b.w;
            acc[2][0] += a2 * b.x; acc[2][1] += a2 * b.y; acc[2][2] += a2 * b.z; acc[2][3] += a2 * b.w;
            acc[3][0] += a3 * b.x; acc[3][1] += a3 * b.y; acc[3][2] += a3 * b.z; acc[3][3] += a3 * b.w;
        }
        __syncthreads();
    }
    float as_part[4], ad_part[4];
#pragma unroll
    for (int i = 0; i < 4; ++i) { as_part[i] = 0.f; ad_part[i] = 0.f; }
    if (tx < 4) {
#pragma unroll
        for (int i = 0; i < 4; ++i) {
#pragma unroll
            for (int jj = 0; jj < 4; ++jj) {
                int c = tx * 4 + jj;
                as_part[i] += acc[i][jj] * atts[c];
                ad_part[i] += acc[i][jj] * attd[c];
            }
        }
    }
#pragma unroll
    for (int i = 0; i < 4; ++i) {
        float ps = as_part[i], pd = ad_part[i];
        ps += __shfl_xor(ps, 1); ps += __shfl_xor(ps, 2);
        pd += __shfl_xor(pd, 1); pd += __shfl_xor(pd, 2);
        int r = row0 + ty * 4 + i;
        if (r < M) {
            if (tx == 0) { aS[r] = ps; aD[r] = pd; }
#pragma unroll
            for (int jj = 0; jj < 4; ++jj) {
                int c = col0 + tx * 4 + jj;
                if (c < N) C[(size_t)r * N + c] = f2bf(acc[i][jj]);
            }
        }
    }
}

// ---------------------------------------------------------------------------
// Layer-4 aggregation (H=1, C=16) with FUSED log_softmax. One wave per node.
// ---------------------------------------------------------------------------
template <int C>
__global__ void gat_agg_l4_ls(const unsigned short* __restrict__ ht,
                              const float* __restrict__ as, const float* __restrict__ aD,
                              const int* __restrict__ rowp, const int* __restrict__ colx,
                              const float* __restrict__ bias, float* __restrict__ out, int Nn) {
    int n = blockIdx.x * 4 + (threadIdx.x >> 6);
    int lane = threadIdx.x & 63;
    if (n >= Nn) return;
    float adv = aD[n];
    int b0 = rowp[n], b1 = rowp[n + 1];

    float m = -1e30f, s = 0.f, acc = 0.f;
    for (int c0 = b0; c0 < b1; c0 += 64) {
        int cnt = b1 - c0; if (cnt > 64) cnt = 64;
        int sn = 0; float e = -1e30f;
        if (lane < cnt) {
            sn = colx[c0 + lane];
            float tt = as[sn] + adv;
            e = (tt > 0.f) ? tt : 0.2f * tt;
        }
        float mc = e;
#pragma unroll
        for (int o = 32; o > 0; o >>= 1) mc = fmaxf(mc, __shfl_xor(mc, o));
        float nm = fmaxf(m, mc);
        float sc = __expf(m - nm);
        acc *= sc; s *= sc;
        float p = (lane < cnt) ? __expf(e - nm) : 0.f;
        float ps = p;
#pragma unroll
        for (int o = 32; o > 0; o >>= 1) ps += __shfl_xor(ps, o);
        s += ps; m = nm;

        int j = 0;
        for (; j + 4 <= cnt; j += 4) {
            int s0 = __shfl(sn, j),     s1 = __shfl(sn, j + 1);
            int s2 = __shfl(sn, j + 2), s3 = __shfl(sn, j + 3);
            float p0 = __shfl(p, j),     p1 = __shfl(p, j + 1);
            float p2 = __shfl(p, j + 2), p3 = __shfl(p, j + 3);
            float h0 = 0.f, h1 = 0.f, h2 = 0.f, h3 = 0.f;
            if (lane < C) {
                h0 = bf2f(ht[(size_t)s0 * C + lane]);
                h1 = bf2f(ht[(size_t)s1 * C + lane]);
                h2 = bf2f(ht[(size_t)s2 * C + lane]);
                h3 = bf2f(ht[(size_t)s3 * C + lane]);
            }
            acc += p0 * h0 + p1 * h1 + p2 * h2 + p3 * h3;
        }
        for (; j < cnt; ++j) {
            int sj = __shfl(sn, j);
            float pj = __shfl(p, j);
            float hv = (lane < C) ? bf2f(ht[(size_t)sj * C + lane]) : 0.f;
            acc += pj * hv;
        }
    }
    float v = (lane < C) ? (acc / s + bias[lane]) : -1e30f;
    float mx = v;
#pragma unroll
    for (int o = 8; o > 0; o >>= 1) mx = fmaxf(mx, __shfl_xor(mx, o));
    float ex = (lane < C) ? __expf(v - mx) : 0.f;
#pragma unroll
    for (int o = 8; o > 0; o >>= 1) ex += __shfl_xor(ex, o);
    float l = __logf(ex) + mx;
    if (lane < C) out[(size_t)n * C + lane] = v - l;
}

// ---------------------------------------------------------------------------
// BatchNorm stats, DETERMINISTIC two-stage (no float atomics).
// ---------------------------------------------------------------------------
template <int F>
__global__ __launch_bounds__(256) void bn_stats_det(const float* __restrict__ x,
                                                    float* __restrict__ part,
                                                    long long total) {
    constexpr int R  = 1024 / F;    // column-set repeats per block
    constexpr int NT = F / 4;       // threads in final accumulation
    __shared__ float sd[256 * 9];
    const int t = threadIdx.x;
    long long idx = ((long long)blockIdx.x * 256 + t) * 4;
    const long long stride = (long long)gridDim.x * 1024;
    float s0 = 0, s1 = 0, s2 = 0, s3 = 0, q0 = 0, q1 = 0, q2 = 0, q3 = 0;
    for (; idx < total; idx += stride) {
        float4 v = *(const float4*)(x + idx);
        s0 += v.x; q0 += v.x * v.x;
        s1 += v.y; q1 += v.y * v.y;
        s2 += v.z; q2 += v.z * v.z;
        s3 += v.w; q3 += v.w * v.w;
    }
    sd[t * 9 + 0] = s0; sd[t * 9 + 1] = s1; sd[t * 9 + 2] = s2; sd[t * 9 + 3] = s3;
    sd[t * 9 + 4] = q0; sd[t * 9 + 5] = q1; sd[t * 9 + 6] = q2; sd[t * 9 + 7] = q3;
    __syncthreads();
    if (t < NT) {
        float a[8];
#pragma unroll
        for (int k = 0; k < 8; ++k) a[k] = sd[t * 9 + k];
        for (int r = 1; r < R; ++r)
#pragma unroll
            for (int k = 0; k < 8; ++k) a[k] += sd[(t + r * NT) * 9 + k];
        int col = t * 4;
        float* pb = part + (size_t)blockIdx.x * 2 * F;
#pragma unroll
        for (int k = 0; k < 4; ++k) {
            pb[col + k]     = a[k];
            pb[F + col + k] = a[4 + k];
        }
    }
}

template <int F>
__global__ __launch_bounds__(256) void bn_reduce_par(const float* __restrict__ part,
                                                     const float* __restrict__ gamma,
                                                     const float* __restrict__ beta,
                                                     float* __restrict__ ss,
                                                     float invN) {
    __shared__ float sd[8][33];
    const int t = threadIdx.x;
    const int pr = t >> 5;          // partial-row 0..7
    const int tg = t & 31;          // target 0..31 (0-15 sum, 16-31 sumsq)
    const int c0 = blockIdx.x * 16;
    const int col = (tg < 16) ? (c0 + tg) : (F + c0 + (tg - 16));
    float a = 0.f;
    for (int p = pr; p < BNP; p += 8)          // fixed order, coalesced
        a += part[(size_t)p * 2 * F + col];
    sd[pr][tg] = a;
    __syncthreads();
    if (pr == 0) {
        float tot = sd[0][tg];
#pragma unroll
        for (int r = 1; r < 8; ++r) tot += sd[r][tg];   // fixed serial order
        sd[0][tg] = tot;
    }
    __syncthreads();
    if (t < 16) {
        int c = c0 + t;
        float s = sd[0][t];
        float q = sd[0][16 + t];
        float mu = s * invN;
        float var = q * invN - mu * mu;
        float sc = gamma[c] * rsqrtf(var + 1e-5f);
        ss[c] = sc;
        ss[F + c] = beta[c] - mu * sc;
    }
}

__global__ void bn_apply_elu_bf16(const float* __restrict__ x, const float* __restrict__ ss,
                                  unsigned short* __restrict__ outA,
                                  int Nn, int F, int fmask) {
    long long idx4 = ((long long)blockIdx.x * blockDim.x + threadIdx.x) * 4;
    int row = (int)(idx4 / F);
    ushort4 o = make_ushort4(0, 0, 0, 0);
    if (row < Nn) {
        int c = (int)(idx4 & fmask);
        float4 v = *(const float4*)(x + idx4);
        float v0 = v.x * ss[c + 0] + ss[F + c + 0];
        float v1 = v.y * ss[c + 1] + ss[F + c + 1];
        float v2 = v.z * ss[c + 2] + ss[F + c + 2];
        float v3 = v.w * ss[c + 3] + ss[F + c + 3];
        v0 = (v0 > 0.f) ? v0 : (__expf(v0) - 1.f);
        v1 = (v1 > 0.f) ? v1 : (__expf(v1) - 1.f);
        v2 = (v2 > 0.f) ? v2 : (__expf(v2) - 1.f);
        v3 = (v3 > 0.f) ? v3 : (__expf(v3) - 1.f);
        o.x = f2bf(v0); o.y = f2bf(v1); o.z = f2bf(v2); o.w = f2bf(v3);
    }
    *(ushort4*)(outA + idx4) = o;
}

// ---------------------------------------------------------------------------
// Launcher
// ---------------------------------------------------------------------------
extern "C" void kernel_launch(void* const* d_in, const int* in_sizes, int n_in,
                              void* d_out, int out_size, void* d_ws, size_t ws_size,
                              hipStream_t stream) {
    const float* x   = (const float*)d_in[0];
    const int*   ei  = (const int*)d_in[1];
    const float* W1  = (const float*)d_in[2];
    const float* as1 = (const float*)d_in[3];
    const float* ad1 = (const float*)d_in[4];
    const float* b1  = (const float*)d_in[5];
    const float* ga1 = (const float*)d_in[6];
    const float* be1 = (const float*)d_in[7];
    const float* W2  = (const float*)d_in[8];
    const float* as2 = (const float*)d_in[9];
    const float* ad2 = (const float*)d_in[10];
    const float* b2  = (const float*)d_in[11];
    const float* ga2 = (const float*)d_in[12];
    const float* be2 = (const float*)d_in[13];
    const float* W3  = (const float*)d_in[14];
    const float* as3 = (const float*)d_in[15];
    const float* ad3 = (const float*)d_in[16];
    const float* b3  = (const float*)d_in[17];
    const float* ga3 = (const float*)d_in[18];
    const float* be3 = (const float*)d_in[19];
    const float* W4  = (const float*)d_in[20];
    const float* as4 = (const float*)d_in[21];
    const float* ad4 = (const float*)d_in[22];
    const float* b4  = (const float*)d_in[23];
    float* outp = (float*)d_out;

    uint8_t* base = (uint8_t*)d_ws;
    size_t off = 0;
    auto alloc = [&](size_t nbytes) -> void* {
        off = (off + 255) & ~(size_t)255;
        void* p = base + off;
        off += nbytes;
        return p;
    };
    float* bufO = (float*)alloc((size_t)NN * 512 * 4);                       // agg out (fp32, BN in)
    unsigned short* bufA = (unsigned short*)alloc((size_t)MPAD * 512 * 2);   // bf16 GEMM A
    unsigned short* hN   = (unsigned short*)alloc((size_t)NN * 512 * 2);     // bf16 node-major h
    unsigned short* Wt1  = (unsigned short*)alloc((size_t)512 * 512 * 2);
    unsigned short* Wt2  = (unsigned short*)alloc((size_t)256 * 512 * 2);
    unsigned short* Wt3  = (unsigned short*)alloc((size_t)128 * 256 * 2);
    float* aSn  = (float*)alloc((size_t)NN * 8 * 4);
    float* aDn  = (float*)alloc((size_t)NN * 8 * 4);
    int*   cnt  = (int*)alloc((size_t)NN * 4);
    int*   rowp = (int*)alloc((size_t)(NN + 1) * 4);
    int*   wptr = (int*)alloc((size_t)NN * 4);
    int*   colx = (int*)alloc((size_t)ET * 4);
    float* bnp  = (float*)alloc((size_t)BNP * 1024 * 4);     // BN partials [BNP][2F]
    float* bns  = (float*)alloc((size_t)1024 * 4);           // scale/shift

    const int* srcRow = ei;
    const int* dstRow = ei + EE;

    // ---- CSR build ----
    zero_i32<<<(NN + 255) / 256, 256, 0, stream>>>(cnt, NN);
    count_edges<<<(ET + 255) / 256, 256, 0, stream>>>(dstRow, cnt);
    scan_fast<<<1, 1024, 0, stream>>>(cnt, rowp, wptr, NN);
    fill_edges<<<(ET + 255) / 256, 256, 0, stream>>>(srcRow, dstRow, wptr, colx);

    // ---- Weight transposes+casts (once) ----
    cvt_w_t<<<(512 * 512 + 255) / 256, 256, 0, stream>>>(W1, Wt1, 512, 512);
    cvt_w_t<<<(512 * 256 + 255) / 256, 256, 0, stream>>>(W2, Wt2, 512, 256);
    cvt_w_t<<<(256 * 128 + 255) / 256, 256, 0, stream>>>(W3, Wt3, 256, 128);

    // ---- Layer 1: Fin=512, H=8, C=64 (F=512) ----
    {
        cvt_a_bf16<<<((MPAD * 512 / 4) + 255) / 256, 256, 0, stream>>>(x, bufA, NN, MPAD, 512);
        dim3 g(512 / 128, MPAD / 128);
        gemm_bf16_fused<<<g, 256, 0, stream>>>(bufA, Wt1, hN, aSn, aDn, as1, ad1, NN, 512, 512);
        gat_agg_all<8><<<NN / 4, 256, 0, stream>>>(hN, aSn, aDn, rowp, colx, b1, bufO, NN);
        bn_stats_det<512><<<BNP, 256, 0, stream>>>(bufO, bnp, (long long)NN * 512);
        bn_reduce_par<512><<<512 / 16, 256, 0, stream>>>(bnp, ga1, be1, bns, 1.0f / NN);
        bn_apply_elu_bf16<<<(MPAD * 512 / 4) / 256, 256, 0, stream>>>(bufO, bns, bufA, NN, 512, 511);
    }
    // ---- Layer 2: Fin=512, H=4, C=64 (F=256) ----
    {
        dim3 g(256 / 128, MPAD / 128);
        gemm_bf16_fused<<<g, 256, 0, stream>>>(bufA, Wt2, hN, aSn, aDn, as2, ad2, NN, 256, 512);
        gat_agg_all<4><<<NN / 4, 256, 0, stream>>>(hN, aSn, aDn, rowp, colx, b2, bufO, NN);
        bn_stats_det<256><<<BNP, 256, 0, stream>>>(bufO, bnp, (long long)NN * 256);
        bn_reduce_par<256><<<256 / 16, 256, 0, stream>>>(bnp, ga2, be2, bns, 1.0f / NN);
        bn_apply_elu_bf16<<<(MPAD * 256 / 4) / 256, 256, 0, stream>>>(bufO, bns, bufA, NN, 256, 255);
    }
    // ---- Layer 3: Fin=256, H=2, C=64 (F=128) ----
    {
        dim3 g(128 / 128, MPAD / 128);
        gemm_bf16_fused<<<g, 256, 0, stream>>>(bufA, Wt3, hN, aSn, aDn, as3, ad3, NN, 128, 256);
        gat_agg_all<2><<<NN / 4, 256, 0, stream>>>(hN, aSn, aDn, rowp, colx, b3, bufO, NN);
        bn_stats_det<128><<<BNP, 256, 0, stream>>>(bufO, bnp, (long long)NN * 128);
        bn_reduce_par<128><<<128 / 16, 256, 0, stream>>>(bnp, ga3, be3, bns, 1.0f / NN);
        bn_apply_elu_bf16<<<(MPAD * 128 / 4) / 256, 256, 0, stream>>>(bufO, bns, bufA, NN, 128, 127);
    }
    // ---- Layer 4: Fin=128, H=1, C=16 + fused att dots + fused log_softmax ----
    {
        dim3 g(1, (NN + 63) / 64);
        gemm_l4_fused<<<g, 256, 0, stream>>>(bufA, W4, hN, aSn, aDn, as4, ad4, NN, 16, 128);
        gat_agg_l4_ls<16><<<(NN + 3) / 4, 256, 0, stream>>>(hN, aSn, aDn, rowp, colx, b4, outp, NN);
    }
}

// Round 12
// 465.446 us; speedup vs baseline: 1.0318x; 1.0318x over previous
//
#include <hip/hip_runtime.h>
#include <hip/hip_bf16.h>
#include <cstdint>
#include <cstddef>

// Problem constants
#define NN 20000
#define EE 320000
#define ET (EE + NN)     // edges + self loops
#define MPAD 20096       // 157 * 128, M padded to tile
#define BNP 256          // BN stage-1 partial blocks (deterministic)
#define SCHUNK 20        // scan_fast: counts per thread (1024*20 >= NN)

typedef __attribute__((ext_vector_type(8))) short  short8;   // 8 bf16 (4 VGPRs)
typedef __attribute__((ext_vector_type(4))) float  floatx4;  // MFMA C/D frag

__device__ inline unsigned short f2bf(float f) {   // RNE fp32 -> bf16
    unsigned u = __float_as_uint(f);
    u += 0x7FFFu + ((u >> 16) & 1u);
    return (unsigned short)(u >> 16);
}
__device__ inline float bf2f(unsigned short b) {
    return __uint_as_float(((unsigned)b) << 16);
}
// packed bf16x2 in a uint -> two floats
__device__ inline float bflo(unsigned u) { return __uint_as_float(u << 16); }
__device__ inline float bfhi(unsigned u) { return __uint_as_float(u & 0xFFFF0000u); }

// per-H gather vector type: lane covers H channels = 2H bytes
template <int H> struct VecT;
template <> struct VecT<8> { using T = uint4; };
template <> struct VecT<4> { using T = uint2; };
template <> struct VecT<2> { using T = unsigned; };

// ---------------------------------------------------------------------------
// Utility kernels
// ---------------------------------------------------------------------------
__global__ void zero_i32(int* __restrict__ p, int n) {
    int i = blockIdx.x * blockDim.x + threadIdx.x;
    if (i < n) p[i] = 0;
}

// fp32 [M,K] -> bf16 [Mpad,K], rows >= M zero-filled. 4 elems/thread.
__global__ void cvt_a_bf16(const float* __restrict__ in, unsigned short* __restrict__ out,
                           int M, int Mpad, int K) {
    long long base = ((long long)blockIdx.x * blockDim.x + threadIdx.x) * 4;
    if (base >= (long long)Mpad * K) return;
    int row = (int)(base / K);
    float4 v = make_float4(0.f, 0.f, 0.f, 0.f);
    if (row < M) v = *(const float4*)(in + base);
    ushort4 o;
    o.x = f2bf(v.x); o.y = f2bf(v.y); o.z = f2bf(v.z); o.w = f2bf(v.w);
    *(ushort4*)(out + base) = o;
}

// W [K,N] fp32 -> Wt [N,K] bf16 (once per launch; small)
__global__ void cvt_w_t(const float* __restrict__ W, unsigned short* __restrict__ Wt,
                        int K, int N) {
    int i = blockIdx.x * blockDim.x + threadIdx.x;
    if (i >= K * N) return;
    int k = i / N, n = i - k * N;
    Wt[(size_t)n * K + k] = f2bf(W[i]);
}

// ---------------------------------------------------------------------------
// CSR build: count -> scan_fast -> fill
// scan_fast: 1 block x 1024 thr; thread t serially scans its 20 contiguous
// counts in registers; one 1024-wide LDS Hillis-Steele (20 barriers, not 400).
// ---------------------------------------------------------------------------
__global__ void count_edges(const int* __restrict__ dst, int* __restrict__ cnt) {
    int e = blockIdx.x * blockDim.x + threadIdx.x;
    if (e >= ET) return;
    int d = (e < EE) ? dst[e] : (e - EE);
    atomicAdd(&cnt[d], 1);
}

__global__ __launch_bounds__(1024) void scan_fast(const int* __restrict__ cnt,
                                                  int* __restrict__ rowp,
                                                  int* __restrict__ wptr, int n) {
    __shared__ int sums[1024];
    const int t = threadIdx.x;
    const int base = t * SCHUNK;
    int local[SCHUNK];
    int acc = 0;
#pragma unroll
    for (int i = 0; i < SCHUNK; ++i) {
        int idx = base + i;
        int v = (idx < n) ? cnt[idx] : 0;
        local[i] = acc;          // exclusive within thread
        acc += v;
    }
    sums[t] = acc;
    __syncthreads();
    for (int o = 1; o < 1024; o <<= 1) {
        int u = (t >= o) ? sums[t - o] : 0;
        __syncthreads();
        sums[t] += u;
        __syncthreads();
    }
    int excl = sums[t] - acc;    // exclusive prefix of this thread's range
#pragma unroll
    for (int i = 0; i < SCHUNK; ++i) {
        int idx = base + i;
        if (idx < n) { int rp = excl + local[i]; rowp[idx] = rp; wptr[idx] = rp; }
    }
    if (t == 1023) rowp[n] = sums[1023];
}

__global__ void fill_edges(const int* __restrict__ src, const int* __restrict__ dst,
                           int* __restrict__ wptr, int* __restrict__ colx) {
    int e = blockIdx.x * blockDim.x + threadIdx.x;
    if (e >= ET) return;
    int s, d;
    if (e < EE) { s = src[e]; d = dst[e]; } else { s = e - EE; d = e - EE; }
    int pos = atomicAdd(&wptr[d], 1);
    colx[pos] = s;
}

// ---------------------------------------------------------------------------
// BF16 MFMA GEMM with fused epilogue (node-major outputs):
//   - hN[row][col] bf16  (node-major h, col = head*64 + c)
//   - aS[row][head], aD[row][head] fp32 (attention dots), H = N/64
// C[M,N] = A[Mpad,K] * Bt[N,K]^T. 128x128 tile, 4 waves, 16x16x32 MFMA.
// ---------------------------------------------------------------------------
__global__ __launch_bounds__(256) void gemm_bf16_fused(
        const unsigned short* __restrict__ A, const unsigned short* __restrict__ Bt,
        unsigned short* __restrict__ hN, float* __restrict__ aS, float* __restrict__ aD,
        const float* __restrict__ atts, const float* __restrict__ attd,
        int M, int N, int K) {
    __shared__ unsigned short As[128][40];
    __shared__ unsigned short Bs[128][40];
    const int t = threadIdx.x;
    const int lane = t & 63, wave = t >> 6;
    const int wm = wave >> 1, wn = wave & 1;
    const int quad = lane >> 4, mrow = lane & 15;
    const int row0 = blockIdx.y * 128, col0 = blockIdx.x * 128;
    const int srow = t >> 2, schunk = (t & 3) * 8;
    const int H = N >> 6;

    floatx4 acc[4][4];
#pragma unroll
    for (int i = 0; i < 4; ++i)
#pragma unroll
        for (int j = 0; j < 4; ++j)
#pragma unroll
            for (int r = 0; r < 4; ++r) acc[i][j][r] = 0.f;

    for (int k0 = 0; k0 < K; k0 += 32) {
        uint4 ra0 = *(const uint4*)(A  + (size_t)(row0 + srow)      * K + k0 + schunk);
        uint4 ra1 = *(const uint4*)(A  + (size_t)(row0 + srow + 64) * K + k0 + schunk);
        uint4 rb0 = *(const uint4*)(Bt + (size_t)(col0 + srow)      * K + k0 + schunk);
        uint4 rb1 = *(const uint4*)(Bt + (size_t)(col0 + srow + 64) * K + k0 + schunk);
        __syncthreads();
        *(uint4*)&As[srow][schunk]      = ra0;
        *(uint4*)&As[srow + 64][schunk] = ra1;
        *(uint4*)&Bs[srow][schunk]      = rb0;
        *(uint4*)&Bs[srow + 64][schunk] = rb1;
        __syncthreads();

        short8 af[4], bfr[4];
#pragma unroll
        for (int i = 0; i < 4; ++i)
            af[i] = *(const short8*)&As[wm * 64 + i * 16 + mrow][quad * 8];
#pragma unroll
        for (int j = 0; j < 4; ++j)
            bfr[j] = *(const short8*)&Bs[wn * 64 + j * 16 + mrow][quad * 8];
#pragma unroll
        for (int i = 0; i < 4; ++i)
#pragma unroll
            for (int j = 0; j < 4; ++j)
                acc[i][j] = __builtin_amdgcn_mfma_f32_16x16x32_bf16(af[i], bfr[j], acc[i][j], 0, 0, 0);
    }

    // ---- fused epilogue ----
    const int head = (col0 + wn * 64) >> 6;
    float attS[4], attD[4];
#pragma unroll
    for (int j = 0; j < 4; ++j) {
        attS[j] = atts[head * 64 + j * 16 + mrow];
        attD[j] = attd[head * 64 + j * 16 + mrow];
    }

#pragma unroll
    for (int i = 0; i < 4; ++i) {
#pragma unroll
        for (int r = 0; r < 4; ++r) {
            int row = row0 + wm * 64 + i * 16 + quad * 4 + r;
            float ps = acc[i][0][r] * attS[0] + acc[i][1][r] * attS[1]
                     + acc[i][2][r] * attS[2] + acc[i][3][r] * attS[3];
            float pd = acc[i][0][r] * attD[0] + acc[i][1][r] * attD[1]
                     + acc[i][2][r] * attD[2] + acc[i][3][r] * attD[3];
#pragma unroll
            for (int o = 1; o < 16; o <<= 1) {
                ps += __shfl_xor(ps, o);
                pd += __shfl_xor(pd, o);
            }
            if (row < M) {
                if (mrow == 0) {
                    aS[(size_t)row * H + head] = ps;
                    aD[(size_t)row * H + head] = pd;
                }
#pragma unroll
                for (int j = 0; j < 4; ++j)
                    hN[(size_t)row * N + col0 + wn * 64 + j * 16 + mrow] = f2bf(acc[i][j][r]);
            }
        }
    }
}

// ---------------------------------------------------------------------------
// GAT aggregation, all heads per wave (round-10/8 two-pass structure —
// measured 56.4-56.9 us, 82K LDS conflicts; the single-chunk "fast path"
// variant regressed to 68 us / 580K conflicts by defeating ds_write
// vectorization — do not reintroduce).
// ---------------------------------------------------------------------------
template <int H>
__global__ __launch_bounds__(256) void gat_agg_all(
        const unsigned short* __restrict__ hN,
        const float* __restrict__ aS, const float* __restrict__ aD,
        const int* __restrict__ rowp, const int* __restrict__ colx,
        const float* __restrict__ bias, float* __restrict__ out, int Nn) {
    constexpr int F = H * 64;
    using V = typename VecT<H>::T;
    __shared__ float pbuf[4][64 * H];
    __shared__ int   snbuf[4][64];
    const int wave = threadIdx.x >> 6, lane = threadIdx.x & 63;
    const int n = blockIdx.x * 4 + wave;
    if (n >= Nn) return;
    const int hd = (lane * H) >> 6;       // this lane's head
    const int chbase = lane * H;          // flat channel base

    const int b0 = rowp[n], b1 = rowp[n + 1];

    float adv[H];
#pragma unroll
    for (int h = 0; h < H; ++h) adv[h] = aD[(size_t)n * H + h];   // broadcast

    // ---- pass 1: per-head m, s ----
    float m[H], s[H];
#pragma unroll
    for (int h = 0; h < H; ++h) { m[h] = -1e30f; s[h] = 0.f; }
    for (int c0 = b0; c0 < b1; c0 += 64) {
        int cnt = min(64, b1 - c0);
        float e[H];
#pragma unroll
        for (int h = 0; h < H; ++h) e[h] = -1e30f;
        if (lane < cnt) {
            int sn = colx[c0 + lane];
#pragma unroll
            for (int h = 0; h < H; ++h) {
                float tt = aS[(size_t)sn * H + h] + adv[h];
                e[h] = (tt > 0.f) ? tt : 0.2f * tt;
            }
        }
#pragma unroll
        for (int h = 0; h < H; ++h) {
            float mc = e[h];
#pragma unroll
            for (int o = 32; o > 0; o >>= 1) mc = fmaxf(mc, __shfl_xor(mc, o));
            float nm = fmaxf(m[h], mc);
            s[h] *= __expf(m[h] - nm);
            float p = (lane < cnt) ? __expf(e[h] - nm) : 0.f;
#pragma unroll
            for (int o = 32; o > 0; o >>= 1) p += __shfl_xor(p, o);
            s[h] += p; m[h] = nm;
        }
    }
    float inv[H];
#pragma unroll
    for (int h = 0; h < H; ++h) inv[h] = 1.f / s[h];

    // ---- pass 2: probs -> LDS, vectorized coalesced gather ----
    float acc[H];
#pragma unroll
    for (int h = 0; h < H; ++h) acc[h] = 0.f;

    for (int c0 = b0; c0 < b1; c0 += 64) {
        int cnt = min(64, b1 - c0);
        if (lane < cnt) {
            int sn = colx[c0 + lane];
            snbuf[wave][lane] = sn;
#pragma unroll
            for (int h = 0; h < H; ++h) {
                float tt = aS[(size_t)sn * H + h] + adv[h];
                tt = (tt > 0.f) ? tt : 0.2f * tt;
                pbuf[wave][lane * H + h] = __expf(tt - m[h]) * inv[h];
            }
        }
        __threadfence_block();   // LDS writes visible before reads (intra-wave)

        int j = 0;
        for (; j + 4 <= cnt; j += 4) {
            int s0 = snbuf[wave][j],     s1 = snbuf[wave][j + 1];
            int s2 = snbuf[wave][j + 2], s3 = snbuf[wave][j + 3];
            float p0 = pbuf[wave][(j + 0) * H + hd];
            float p1 = pbuf[wave][(j + 1) * H + hd];
            float p2 = pbuf[wave][(j + 2) * H + hd];
            float p3 = pbuf[wave][(j + 3) * H + hd];
            V q0 = *(const V*)(hN + (size_t)s0 * F + chbase);
            V q1 = *(const V*)(hN + (size_t)s1 * F + chbase);
            V q2 = *(const V*)(hN + (size_t)s2 * F + chbase);
            V q3 = *(const V*)(hN + (size_t)s3 * F + chbase);
            const unsigned* u0 = (const unsigned*)&q0;
            const unsigned* u1 = (const unsigned*)&q1;
            const unsigned* u2 = (const unsigned*)&q2;
            const unsigned* u3 = (const unsigned*)&q3;
#pragma unroll
            for (int k = 0; k < H / 2; ++k) {
                acc[2 * k]     += p0 * bflo(u0[k]) + p1 * bflo(u1[k]) + p2 * bflo(u2[k]) + p3 * bflo(u3[k]);
                acc[2 * k + 1] += p0 * bfhi(u0[k]) + p1 * bfhi(u1[k]) + p2 * bfhi(u2[k]) + p3 * bfhi(u3[k]);
            }
        }
        for (; j < cnt; ++j) {
            int sj = snbuf[wave][j];
            float pj = pbuf[wave][j * H + hd];
            V q = *(const V*)(hN + (size_t)sj * F + chbase);
            const unsigned* u = (const unsigned*)&q;
#pragma unroll
            for (int k = 0; k < H / 2; ++k) {
                acc[2 * k]     += pj * bflo(u[k]);
                acc[2 * k + 1] += pj * bfhi(u[k]);
            }
        }
        __threadfence_block();   // reads done before next chunk overwrites
    }

#pragma unroll
    for (int h = 0; h < H; ++h)
        out[(size_t)n * F + chbase + h] = acc[h] + bias[chbase + h];
}

// ---------------------------------------------------------------------------
// Layer-4 GEMM: A is bf16 [Mpad,K], N=16. Writes bf16 hN and fused attention
// dots aS/aD (H=1, C=16). 64x64 tile; only tx<4 columns are real (N=16).
// ---------------------------------------------------------------------------
__global__ __launch_bounds__(256) void gemm_l4_fused(const unsigned short* __restrict__ A,
                                                     const float* __restrict__ B,
                                                     unsigned short* __restrict__ C,
                                                     float* __restrict__ aS, float* __restrict__ aD,
                                                     const float* __restrict__ atts,
                                                     const float* __restrict__ attd,
                                                     int M, int N, int K) {
    __shared__ float As[16][65];
    __shared__ float Bs[16][64];
    const int tid = threadIdx.x;
    const int tx = tid & 15, ty = tid >> 4;
    const int row0 = blockIdx.y * 64, col0 = blockIdx.x * 64;
    const int rA = tid >> 2, kq = (tid & 3) << 2;
    const int rB = tid >> 4, cq = (tid & 15) << 2;
    float acc[4][4] = {};

    for (int k0 = 0; k0 < K; k0 += 16) {
        ushort4 ha = *(const ushort4*)(A + (size_t)(row0 + rA) * K + k0 + kq);
        float4 fb = make_float4(0.f, 0.f, 0.f, 0.f);
        int bcol = col0 + cq;
        if (bcol < N) fb = *(const float4*)(B + (size_t)(k0 + rB) * N + bcol);
        As[kq + 0][rA] = bf2f(ha.x); As[kq + 1][rA] = bf2f(ha.y);
        As[kq + 2][rA] = bf2f(ha.z); As[kq + 3][rA] = bf2f(ha.w);
        *(float4*)&Bs[rB][cq] = fb;
        __syncthreads();
#pragma unroll
        for (int k = 0; k < 16; ++k) {
            float a0 = As[k][ty * 4 + 0];
            float a1 = As[k][ty * 4 + 1];
            float a2 = As[k][ty * 4 + 2];
            float a3 = As[k][ty * 4 + 3];
            float4 b = *(float4*)&Bs[k][tx * 4];
            acc[0][0] += a0 * b.x; acc[0][1] += a0 * b.y; acc[0][2] += a0 * b.z; acc[0][3] += a0 * b.w;
            acc[1][0] += a1 * b.x; acc[1][1] += a1 * b.y; acc[1][2] += a1 * b.z; acc[1][3] += a1 * b.w;
            acc[2][0] += a2 * b.x; acc[2][1] += a2 * b.y; acc[2][2] += a2 * b.z; acc[2][3] += a2 * b.w;
            acc[3][0] += a3 * b.x; acc[3][1] += a3 * b.y; acc[3][2] += a3 * b.z; acc[3][3] += a3 * b.w;
        }
        __syncthreads();
    }
    float as_part[4], ad_part[4];
#pragma unroll
    for (int i = 0; i < 4; ++i) { as_part[i] = 0.f; ad_part[i] = 0.f; }
    if (tx < 4) {
#pragma unroll
        for (int i = 0; i < 4; ++i) {
#pragma unroll
            for (int jj = 0; jj < 4; ++jj) {
                int c = tx * 4 + jj;
                as_part[i] += acc[i][jj] * atts[c];
                ad_part[i] += acc[i][jj] * attd[c];
            }
        }
    }
#pragma unroll
    for (int i = 0; i < 4; ++i) {
        float ps = as_part[i], pd = ad_part[i];
        ps += __shfl_xor(ps, 1); ps += __shfl_xor(ps, 2);
        pd += __shfl_xor(pd, 1); pd += __shfl_xor(pd, 2);
        int r = row0 + ty * 4 + i;
        if (r < M) {
            if (tx == 0) { aS[r] = ps; aD[r] = pd; }
#pragma unroll
            for (int jj = 0; jj < 4; ++jj) {
                int c = col0 + tx * 4 + jj;
                if (c < N) C[(size_t)r * N + c] = f2bf(acc[i][jj]);
            }
        }
    }
}

// ---------------------------------------------------------------------------
// Layer-4 aggregation (H=1, C=16) with FUSED log_softmax. One wave per node.
// ---------------------------------------------------------------------------
template <int C>
__global__ void gat_agg_l4_ls(const unsigned short* __restrict__ ht,
                              const float* __restrict__ as, const float* __restrict__ aD,
                              const int* __restrict__ rowp, const int* __restrict__ colx,
                              const float* __restrict__ bias, float* __restrict__ out, int Nn) {
    int n = blockIdx.x * 4 + (threadIdx.x >> 6);
    int lane = threadIdx.x & 63;
    if (n >= Nn) return;
    float adv = aD[n];
    int b0 = rowp[n], b1 = rowp[n + 1];

    float m = -1e30f, s = 0.f, acc = 0.f;
    for (int c0 = b0; c0 < b1; c0 += 64) {
        int cnt = b1 - c0; if (cnt > 64) cnt = 64;
        int sn = 0; float e = -1e30f;
        if (lane < cnt) {
            sn = colx[c0 + lane];
            float tt = as[sn] + adv;
            e = (tt > 0.f) ? tt : 0.2f * tt;
        }
        float mc = e;
#pragma unroll
        for (int o = 32; o > 0; o >>= 1) mc = fmaxf(mc, __shfl_xor(mc, o));
        float nm = fmaxf(m, mc);
        float sc = __expf(m - nm);
        acc *= sc; s *= sc;
        float p = (lane < cnt) ? __expf(e - nm) : 0.f;
        float ps = p;
#pragma unroll
        for (int o = 32; o > 0; o >>= 1) ps += __shfl_xor(ps, o);
        s += ps; m = nm;

        int j = 0;
        for (; j + 4 <= cnt; j += 4) {
            int s0 = __shfl(sn, j),     s1 = __shfl(sn, j + 1);
            int s2 = __shfl(sn, j + 2), s3 = __shfl(sn, j + 3);
            float p0 = __shfl(p, j),     p1 = __shfl(p, j + 1);
            float p2 = __shfl(p, j + 2), p3 = __shfl(p, j + 3);
            float h0 = 0.f, h1 = 0.f, h2 = 0.f, h3 = 0.f;
            if (lane < C) {
                h0 = bf2f(ht[(size_t)s0 * C + lane]);
                h1 = bf2f(ht[(size_t)s1 * C + lane]);
                h2 = bf2f(ht[(size_t)s2 * C + lane]);
                h3 = bf2f(ht[(size_t)s3 * C + lane]);
            }
            acc += p0 * h0 + p1 * h1 + p2 * h2 + p3 * h3;
        }
        for (; j < cnt; ++j) {
            int sj = __shfl(sn, j);
            float pj = __shfl(p, j);
            float hv = (lane < C) ? bf2f(ht[(size_t)sj * C + lane]) : 0.f;
            acc += pj * hv;
        }
    }
    float v = (lane < C) ? (acc / s + bias[lane]) : -1e30f;
    float mx = v;
#pragma unroll
    for (int o = 8; o > 0; o >>= 1) mx = fmaxf(mx, __shfl_xor(mx, o));
    float ex = (lane < C) ? __expf(v - mx) : 0.f;
#pragma unroll
    for (int o = 8; o > 0; o >>= 1) ex += __shfl_xor(ex, o);
    float l = __logf(ex) + mx;
    if (lane < C) out[(size_t)n * C + lane] = v - l;
}

// ---------------------------------------------------------------------------
// BatchNorm stats, DETERMINISTIC two-stage (no float atomics).
// ---------------------------------------------------------------------------
template <int F>
__global__ __launch_bounds__(256) void bn_stats_det(const float* __restrict__ x,
                                                    float* __restrict__ part,
                                                    long long total) {
    constexpr int R  = 1024 / F;    // column-set repeats per block
    constexpr int NT = F / 4;       // threads in final accumulation
    __shared__ float sd[256 * 9];
    const int t = threadIdx.x;
    long long idx = ((long long)blockIdx.x * 256 + t) * 4;
    const long long stride = (long long)gridDim.x * 1024;
    float s0 = 0, s1 = 0, s2 = 0, s3 = 0, q0 = 0, q1 = 0, q2 = 0, q3 = 0;
    for (; idx < total; idx += stride) {
        float4 v = *(const float4*)(x + idx);
        s0 += v.x; q0 += v.x * v.x;
        s1 += v.y; q1 += v.y * v.y;
        s2 += v.z; q2 += v.z * v.z;
        s3 += v.w; q3 += v.w * v.w;
    }
    sd[t * 9 + 0] = s0; sd[t * 9 + 1] = s1; sd[t * 9 + 2] = s2; sd[t * 9 + 3] = s3;
    sd[t * 9 + 4] = q0; sd[t * 9 + 5] = q1; sd[t * 9 + 6] = q2; sd[t * 9 + 7] = q3;
    __syncthreads();
    if (t < NT) {
        float a[8];
#pragma unroll
        for (int k = 0; k < 8; ++k) a[k] = sd[t * 9 + k];
        for (int r = 1; r < R; ++r)
#pragma unroll
            for (int k = 0; k < 8; ++k) a[k] += sd[(t + r * NT) * 9 + k];
        int col = t * 4;
        float* pb = part + (size_t)blockIdx.x * 2 * F;
#pragma unroll
        for (int k = 0; k < 4; ++k) {
            pb[col + k]     = a[k];
            pb[F + col + k] = a[4 + k];
        }
    }
}

template <int F>
__global__ __launch_bounds__(256) void bn_reduce_par(const float* __restrict__ part,
                                                     const float* __restrict__ gamma,
                                                     const float* __restrict__ beta,
                                                     float* __restrict__ ss,
                                                     float invN) {
    __shared__ float sd[8][33];
    const int t = threadIdx.x;
    const int pr = t >> 5;          // partial-row 0..7
    const int tg = t & 31;          // target 0..31 (0-15 sum, 16-31 sumsq)
    const int c0 = blockIdx.x * 16;
    const int col = (tg < 16) ? (c0 + tg) : (F + c0 + (tg - 16));
    float a = 0.f;
    for (int p = pr; p < BNP; p += 8)          // fixed order, coalesced
        a += part[(size_t)p * 2 * F + col];
    sd[pr][tg] = a;
    __syncthreads();
    if (pr == 0) {
        float tot = sd[0][tg];
#pragma unroll
        for (int r = 1; r < 8; ++r) tot += sd[r][tg];   // fixed serial order
        sd[0][tg] = tot;
    }
    __syncthreads();
    if (t < 16) {
        int c = c0 + t;
        float s = sd[0][t];
        float q = sd[0][16 + t];
        float mu = s * invN;
        float var = q * invN - mu * mu;
        float sc = gamma[c] * rsqrtf(var + 1e-5f);
        ss[c] = sc;
        ss[F + c] = beta[c] - mu * sc;
    }
}

__global__ void bn_apply_elu_bf16(const float* __restrict__ x, const float* __restrict__ ss,
                                  unsigned short* __restrict__ outA,
                                  int Nn, int F, int fmask) {
    long long idx4 = ((long long)blockIdx.x * blockDim.x + threadIdx.x) * 4;
    int row = (int)(idx4 / F);
    ushort4 o = make_ushort4(0, 0, 0, 0);
    if (row < Nn) {
        int c = (int)(idx4 & fmask);
        float4 v = *(const float4*)(x + idx4);
        float v0 = v.x * ss[c + 0] + ss[F + c + 0];
        float v1 = v.y * ss[c + 1] + ss[F + c + 1];
        float v2 = v.z * ss[c + 2] + ss[F + c + 2];
        float v3 = v.w * ss[c + 3] + ss[F + c + 3];
        v0 = (v0 > 0.f) ? v0 : (__expf(v0) - 1.f);
        v1 = (v1 > 0.f) ? v1 : (__expf(v1) - 1.f);
        v2 = (v2 > 0.f) ? v2 : (__expf(v2) - 1.f);
        v3 = (v3 > 0.f) ? v3 : (__expf(v3) - 1.f);
        o.x = f2bf(v0); o.y = f2bf(v1); o.z = f2bf(v2); o.w = f2bf(v3);
    }
    *(ushort4*)(outA + idx4) = o;
}

// ---------------------------------------------------------------------------
// Launcher
// ---------------------------------------------------------------------------
extern "C" void kernel_launch(void* const* d_in, const int* in_sizes, int n_in,
                              void* d_out, int out_size, void* d_ws, size_t ws_size,
                              hipStream_t stream) {
    const float* x   = (const float*)d_in[0];
    const int*   ei  = (const int*)d_in[1];
    const float* W1  = (const float*)d_in[2];
    const float* as1 = (const float*)d_in[3];
    const float* ad1 = (const float*)d_in[4];
    const float* b1  = (const float*)d_in[5];
    const float* ga1 = (const float*)d_in[6];
    const float* be1 = (const float*)d_in[7];
    const float* W2  = (const float*)d_in[8];
    const float* as2 = (const float*)d_in[9];
    const float* ad2 = (const float*)d_in[10];
    const float* b2  = (const float*)d_in[11];
    const float* ga2 = (const float*)d_in[12];
    const float* be2 = (const float*)d_in[13];
    const float* W3  = (const float*)d_in[14];
    const float* as3 = (const float*)d_in[15];
    const float* ad3 = (const float*)d_in[16];
    const float* b3  = (const float*)d_in[17];
    const float* ga3 = (const float*)d_in[18];
    const float* be3 = (const float*)d_in[19];
    const float* W4  = (const float*)d_in[20];
    const float* as4 = (const float*)d_in[21];
    const float* ad4 = (const float*)d_in[22];
    const float* b4  = (const float*)d_in[23];
    float* outp = (float*)d_out;

    uint8_t* base = (uint8_t*)d_ws;
    size_t off = 0;
    auto alloc = [&](size_t nbytes) -> void* {
        off = (off + 255) & ~(size_t)255;
        void* p = base + off;
        off += nbytes;
        return p;
    };
    float* bufO = (float*)alloc((size_t)NN * 512 * 4);                       // agg out (fp32, BN in)
    unsigned short* bufA = (unsigned short*)alloc((size_t)MPAD * 512 * 2);   // bf16 GEMM A
    unsigned short* hN   = (unsigned short*)alloc((size_t)NN * 512 * 2);     // bf16 node-major h
    unsigned short* Wt1  = (unsigned short*)alloc((size_t)512 * 512 * 2);
    unsigned short* Wt2  = (unsigned short*)alloc((size_t)256 * 512 * 2);
    unsigned short* Wt3  = (unsigned short*)alloc((size_t)128 * 256 * 2);
    float* aSn  = (float*)alloc((size_t)NN * 8 * 4);
    float* aDn  = (float*)alloc((size_t)NN * 8 * 4);
    int*   cnt  = (int*)alloc((size_t)NN * 4);
    int*   rowp = (int*)alloc((size_t)(NN + 1) * 4);
    int*   wptr = (int*)alloc((size_t)NN * 4);
    int*   colx = (int*)alloc((size_t)ET * 4);
    float* bnp  = (float*)alloc((size_t)BNP * 1024 * 4);     // BN partials [BNP][2F]
    float* bns  = (float*)alloc((size_t)1024 * 4);           // scale/shift

    const int* srcRow = ei;
    const int* dstRow = ei + EE;

    // ---- CSR build ----
    zero_i32<<<(NN + 255) / 256, 256, 0, stream>>>(cnt, NN);
    count_edges<<<(ET + 255) / 256, 256, 0, stream>>>(dstRow, cnt);
    scan_fast<<<1, 1024, 0, stream>>>(cnt, rowp, wptr, NN);
    fill_edges<<<(ET + 255) / 256, 256, 0, stream>>>(srcRow, dstRow, wptr, colx);

    // ---- Weight transposes+casts (once) ----
    cvt_w_t<<<(512 * 512 + 255) / 256, 256, 0, stream>>>(W1, Wt1, 512, 512);
    cvt_w_t<<<(512 * 256 + 255) / 256, 256, 0, stream>>>(W2, Wt2, 512, 256);
    cvt_w_t<<<(256 * 128 + 255) / 256, 256, 0, stream>>>(W3, Wt3, 256, 128);

    // ---- Layer 1: Fin=512, H=8, C=64 (F=512) ----
    {
        cvt_a_bf16<<<((MPAD * 512 / 4) + 255) / 256, 256, 0, stream>>>(x, bufA, NN, MPAD, 512);
        dim3 g(512 / 128, MPAD / 128);
        gemm_bf16_fused<<<g, 256, 0, stream>>>(bufA, Wt1, hN, aSn, aDn, as1, ad1, NN, 512, 512);
        gat_agg_all<8><<<NN / 4, 256, 0, stream>>>(hN, aSn, aDn, rowp, colx, b1, bufO, NN);
        bn_stats_det<512><<<BNP, 256, 0, stream>>>(bufO, bnp, (long long)NN * 512);
        bn_reduce_par<512><<<512 / 16, 256, 0, stream>>>(bnp, ga1, be1, bns, 1.0f / NN);
        bn_apply_elu_bf16<<<(MPAD * 512 / 4) / 256, 256, 0, stream>>>(bufO, bns, bufA, NN, 512, 511);
    }
    // ---- Layer 2: Fin=512, H=4, C=64 (F=256) ----
    {
        dim3 g(256 / 128, MPAD / 128);
        gemm_bf16_fused<<<g, 256, 0, stream>>>(bufA, Wt2, hN, aSn, aDn, as2, ad2, NN, 256, 512);
        gat_agg_all<4><<<NN / 4, 256, 0, stream>>>(hN, aSn, aDn, rowp, colx, b2, bufO, NN);
        bn_stats_det<256><<<BNP, 256, 0, stream>>>(bufO, bnp, (long long)NN * 256);
        bn_reduce_par<256><<<256 / 16, 256, 0, stream>>>(bnp, ga2, be2, bns, 1.0f / NN);
        bn_apply_elu_bf16<<<(MPAD * 256 / 4) / 256, 256, 0, stream>>>(bufO, bns, bufA, NN, 256, 255);
    }
    // ---- Layer 3: Fin=256, H=2, C=64 (F=128) ----
    {
        dim3 g(128 / 128, MPAD / 128);
        gemm_bf16_fused<<<g, 256, 0, stream>>>(bufA, Wt3, hN, aSn, aDn, as3, ad3, NN, 128, 256);
        gat_agg_all<2><<<NN / 4, 256, 0, stream>>>(hN, aSn, aDn, rowp, colx, b3, bufO, NN);
        bn_stats_det<128><<<BNP, 256, 0, stream>>>(bufO, bnp, (long long)NN * 128);
        bn_reduce_par<128><<<128 / 16, 256, 0, stream>>>(bnp, ga3, be3, bns, 1.0f / NN);
        bn_apply_elu_bf16<<<(MPAD * 128 / 4) / 256, 256, 0, stream>>>(bufO, bns, bufA, NN, 128, 127);
    }
    // ---- Layer 4: Fin=128, H=1, C=16 + fused att dots + fused log_softmax ----
    {
        dim3 g(1, (NN + 63) / 64);
        gemm_l4_fused<<<g, 256, 0, stream>>>(bufA, W4, hN, aSn, aDn, as4, ad4, NN, 16, 128);
        gat_agg_l4_ls<16><<<(NN + 3) / 4, 256, 0, stream>>>(hN, aSn, aDn, rowp, colx, b4, outp, NN);
    }
}